// Round 1
// baseline (411.266 us; speedup 1.0000x reference)
//
#include <hip/hip_runtime.h>

// AUGRU fused persistent kernel.
// B=1024, T=200, I=128, H=128.
// 64 blocks x 256 threads (4 waves). Block owns 16 batch rows for all T steps.
// Weights kept in VGPRs as MFMA B-fragments. 2 barriers per step.

#define T_N   200
#define I_DIM 128
#define H_DIM 128

typedef float  f32x4   __attribute__((ext_vector_type(4)));
typedef short  short8v __attribute__((ext_vector_type(8)));
typedef __bf16 bf16x8  __attribute__((ext_vector_type(8)));

#define LDA_STRIDE 264   // bf16 elems/row: [h 128 | rh 128 | pad 8] -> 2-way max conflicts
#define LDH_STRIDE 132   // f32 h, padded
#define LDZ_STRIDE 132   // f32 z' = a*z, padded
#define LATT_STRIDE 201  // f32 attention, padded

__device__ __forceinline__ unsigned short f2bf(float f) {
  unsigned u = __builtin_bit_cast(unsigned, f);
  return (unsigned short)((u + 0x7FFFu + ((u >> 16) & 1u)) >> 16);  // RNE
}

__device__ __forceinline__ bf16x8 pack8(float4 a, float4 b) {
  short8v t;
  t[0] = (short)f2bf(a.x); t[1] = (short)f2bf(a.y);
  t[2] = (short)f2bf(a.z); t[3] = (short)f2bf(a.w);
  t[4] = (short)f2bf(b.x); t[5] = (short)f2bf(b.y);
  t[6] = (short)f2bf(b.z); t[7] = (short)f2bf(b.w);
  return __builtin_bit_cast(bf16x8, t);
}

__device__ __forceinline__ float fast_sigmoid(float x) {
  float e = __builtin_amdgcn_exp2f(-1.4426950408889634f * x);   // e^-x
  return __builtin_amdgcn_rcpf(1.0f + e);
}
__device__ __forceinline__ float fast_tanh(float x) {
  float e = __builtin_amdgcn_exp2f(2.8853900817779268f * x);    // e^(2x)
  return 1.0f - 2.0f * __builtin_amdgcn_rcpf(1.0f + e);
}

__global__ __launch_bounds__(256, 1)
void augru_kernel(const float* __restrict__ inputs,
                  const float* __restrict__ attn,
                  const float* __restrict__ Wz, const float* __restrict__ bz,
                  const float* __restrict__ Wr, const float* __restrict__ br,
                  const float* __restrict__ Wh, const float* __restrict__ bh,
                  float* __restrict__ out) {
  __shared__ __align__(16) short lds_a[16 * LDA_STRIDE];  // bf16 bits: [h | rh]
  __shared__ float lds_hf[16 * LDH_STRIDE];               // h (f32)
  __shared__ float lds_z[16 * LDZ_STRIDE];                // z' = a_t * sigmoid(z_pre)
  __shared__ float lds_att[16 * LATT_STRIDE];             // attention slice

  const int tid = threadIdx.x;
  const int w   = tid >> 6;        // wave 0..3
  const int l   = tid & 63;
  const int l15 = l & 15;
  const int lk  = l >> 4;          // k-group 0..3
  const int r0  = blockIdx.x * 16; // batch row base

  // ---- prologue: attention slice -> LDS, zero h ----
  for (int idx = tid; idx < 16 * T_N; idx += 256) {
    int row = idx / T_N, t = idx - row * T_N;
    lds_att[row * LATT_STRIDE + t] = attn[(size_t)(r0 + row) * T_N + t];
  }
  for (int idx = tid; idx < 16 * H_DIM; idx += 256) {
    int row = idx >> 7, c = idx & 127;
    lds_hf[row * LDH_STRIDE + c] = 0.0f;
    lds_a[row * LDA_STRIDE + c]  = 0;
  }

  // ---- weights -> VGPR fragments ----
  // phase1 B-frags: output col n = w*64 + ct*16 + l15 ; n<128 -> Wz row n, else Wr row n-128
  // frag(ct,kt) lane l: W[n][kt*32 + lk*8 + e], e=0..7 (contiguous in W's row)
  bf16x8 w1[32];
  float  bias1[4];
  #pragma unroll
  for (int ct = 0; ct < 4; ++ct) {
    int n = w * 64 + ct * 16 + l15;
    const float* Wp;
    float bv;
    if (n < 128) { Wp = Wz + (size_t)n * 256;         bv = bz[n]; }
    else         { Wp = Wr + (size_t)(n - 128) * 256; bv = br[n - 128]; }
    bias1[ct] = bv;
    #pragma unroll
    for (int kt = 0; kt < 8; ++kt) {
      const float* p = Wp + kt * 32 + lk * 8;
      w1[ct * 8 + kt] = pack8(*(const float4*)p, *(const float4*)(p + 4));
    }
  }
  // phase2 B-frags: col n = w*32 + ct*16 + l15 -> Wh row n
  bf16x8 w2[16];
  float  bias2[2];
  #pragma unroll
  for (int ct = 0; ct < 2; ++ct) {
    int n = w * 32 + ct * 16 + l15;
    bias2[ct] = bh[n];
    const float* Wp = Wh + (size_t)n * 256;
    #pragma unroll
    for (int kt = 0; kt < 8; ++kt) {
      const float* p = Wp + kt * 32 + lk * 8;
      w2[ct * 8 + kt] = pack8(*(const float4*)p, *(const float4*)(p + 4));
    }
  }

  // ---- x fragments for t=0 (direct from global, per-wave redundant, L1-served) ----
  const float* xbase = inputs + (size_t)(r0 + l15) * (T_N * I_DIM);
  bf16x8 xfrag[4];
  #pragma unroll
  for (int kt = 0; kt < 4; ++kt) {
    const float* p = xbase + kt * 32 + lk * 8;
    xfrag[kt] = pack8(*(const float4*)p, *(const float4*)(p + 4));
  }

  __syncthreads();

  float4 xr0[4], xr1[4];  // raw f32 prefetch for t+1
  for (int t = 0; t < T_N; ++t) {
    // ---- issue x_{t+1} prefetch early ----
    if (t + 1 < T_N) {
      #pragma unroll
      for (int kt = 0; kt < 4; ++kt) {
        const float* p = xbase + (size_t)(t + 1) * I_DIM + kt * 32 + lk * 8;
        xr0[kt] = *(const float4*)p;
        xr1[kt] = *(const float4*)(p + 4);
      }
    }

    // ---- phase 1: [x|h] @ [Wz;Wr]^T ----
    bf16x8 hfrag[4];
    #pragma unroll
    for (int kt = 0; kt < 4; ++kt)
      hfrag[kt] = *(const bf16x8*)&lds_a[l15 * LDA_STRIDE + kt * 32 + lk * 8];

    f32x4 acc[4];
    #pragma unroll
    for (int ct = 0; ct < 4; ++ct) {
      f32x4 a; a[0] = bias1[ct]; a[1] = bias1[ct]; a[2] = bias1[ct]; a[3] = bias1[ct];
      acc[ct] = a;
    }
    #pragma unroll
    for (int kt = 0; kt < 4; ++kt)
      #pragma unroll
      for (int ct = 0; ct < 4; ++ct)
        acc[ct] = __builtin_amdgcn_mfma_f32_16x16x32_bf16(xfrag[kt], w1[ct * 8 + kt], acc[ct], 0, 0, 0);
    #pragma unroll
    for (int kt = 0; kt < 4; ++kt)
      #pragma unroll
      for (int ct = 0; ct < 4; ++ct)
        acc[ct] = __builtin_amdgcn_mfma_f32_16x16x32_bf16(hfrag[kt], w1[ct * 8 + 4 + kt], acc[ct], 0, 0, 0);

    // ---- apply gates (C/D layout: col = l15, row = lk*4 + q) ----
    if (w < 2) {            // z-waves: z' = a_t * sigmoid(z_pre)
      float av[4];
      #pragma unroll
      for (int q = 0; q < 4; ++q) av[q] = lds_att[(lk * 4 + q) * LATT_STRIDE + t];
      #pragma unroll
      for (int ct = 0; ct < 4; ++ct) {
        int col = w * 64 + ct * 16 + l15;
        #pragma unroll
        for (int q = 0; q < 4; ++q) {
          int row = lk * 4 + q;
          lds_z[row * LDZ_STRIDE + col] = av[q] * fast_sigmoid(acc[ct][q]);
        }
      }
    } else {                // r-waves: rh = sigmoid(r_pre) * h  (bf16 -> A-buffer)
      #pragma unroll
      for (int ct = 0; ct < 4; ++ct) {
        int col = (w - 2) * 64 + ct * 16 + l15;
        #pragma unroll
        for (int q = 0; q < 4; ++q) {
          int row = lk * 4 + q;
          float rr = fast_sigmoid(acc[ct][q]);
          float hv = lds_hf[row * LDH_STRIDE + col];
          lds_a[row * LDA_STRIDE + 128 + col] = (short)f2bf(rr * hv);
        }
      }
    }
    __syncthreads();  // (1) rh + z' visible

    // ---- phase 2: [x|rh] @ Wh^T ----
    bf16x8 rfrag[4];
    #pragma unroll
    for (int kt = 0; kt < 4; ++kt)
      rfrag[kt] = *(const bf16x8*)&lds_a[l15 * LDA_STRIDE + 128 + kt * 32 + lk * 8];

    f32x4 acc2[2];
    #pragma unroll
    for (int ct = 0; ct < 2; ++ct) {
      f32x4 a; a[0] = bias2[ct]; a[1] = bias2[ct]; a[2] = bias2[ct]; a[3] = bias2[ct];
      acc2[ct] = a;
    }
    #pragma unroll
    for (int kt = 0; kt < 4; ++kt)
      #pragma unroll
      for (int ct = 0; ct < 2; ++ct)
        acc2[ct] = __builtin_amdgcn_mfma_f32_16x16x32_bf16(xfrag[kt], w2[ct * 8 + kt], acc2[ct], 0, 0, 0);
    #pragma unroll
    for (int kt = 0; kt < 4; ++kt)
      #pragma unroll
      for (int ct = 0; ct < 2; ++ct)
        acc2[ct] = __builtin_amdgcn_mfma_f32_16x16x32_bf16(rfrag[kt], w2[ct * 8 + 4 + kt], acc2[ct], 0, 0, 0);

    // convert prefetched x for the next step (after last use of current xfrag)
    if (t + 1 < T_N) {
      #pragma unroll
      for (int kt = 0; kt < 4; ++kt)
        xfrag[kt] = pack8(xr0[kt], xr1[kt]);
    }

    // ---- update: h_new = h + z' * (tanh(h_pre) - h) ----
    #pragma unroll
    for (int ct = 0; ct < 2; ++ct) {
      int col = w * 32 + ct * 16 + l15;
      #pragma unroll
      for (int q = 0; q < 4; ++q) {
        int row = lk * 4 + q;
        float ht = fast_tanh(acc2[ct][q]);
        float zp = lds_z[row * LDZ_STRIDE + col];
        float ho = lds_hf[row * LDH_STRIDE + col];
        float hn = __builtin_fmaf(zp, ht - ho, ho);
        lds_hf[row * LDH_STRIDE + col] = hn;
        lds_a[row * LDA_STRIDE + col]  = (short)f2bf(hn);
      }
    }
    __syncthreads();  // (2) h visible for next phase-1
  }

  // ---- epilogue: write final h ----
  {
    int row = tid >> 4, c0 = (tid & 15) * 8;
    #pragma unroll
    for (int j = 0; j < 8; ++j)
      out[(size_t)(r0 + row) * H_DIM + c0 + j] = lds_hf[row * LDH_STRIDE + c0 + j];
  }
}

extern "C" void kernel_launch(void* const* d_in, const int* in_sizes, int n_in,
                              void* d_out, int out_size, void* d_ws, size_t ws_size,
                              hipStream_t stream) {
  (void)in_sizes; (void)n_in; (void)out_size; (void)d_ws; (void)ws_size;
  const float* inputs = (const float*)d_in[0];
  const float* attn   = (const float*)d_in[1];
  const float* Wz     = (const float*)d_in[2];
  const float* bz     = (const float*)d_in[3];
  const float* Wr     = (const float*)d_in[4];
  const float* br     = (const float*)d_in[5];
  const float* Wh     = (const float*)d_in[6];
  const float* bh     = (const float*)d_in[7];
  float* out = (float*)d_out;
  augru_kernel<<<64, 256, 0, stream>>>(inputs, attn, Wz, bz, Wr, br, Wh, bh, out);
}

// Round 2
// 410.272 us; speedup vs baseline: 1.0024x; 1.0024x over previous
//
#include <hip/hip_runtime.h>

// AUGRU fused persistent kernel, round 2.
// B=1024, T=200, I=128, H=128.
// 64 blocks x 256 threads (4 waves). Block owns 16 batch rows for all T steps.
// Weights in VGPRs as MFMA B-fragments. Per-wave column ownership unified
// across phase1(z,r)/phase2(h~)/update so z' and h(f32) stay in registers.
// Raw s_barrier (lgkmcnt only) so the x prefetch survives barriers in flight.

#define T_N   200
#define I_DIM 128
#define H_DIM 128

typedef float  f32x4   __attribute__((ext_vector_type(4)));
typedef short  short8v __attribute__((ext_vector_type(8)));
typedef __bf16 bf16x8  __attribute__((ext_vector_type(8)));

#define LDA_STRIDE 264   // bf16 elems/row: [h 128 | rh 128 | pad 8]
#define LATT_STRIDE 201  // f32 attention, padded

__device__ __forceinline__ unsigned short f2bf(float f) {
  unsigned u = __builtin_bit_cast(unsigned, f);
  return (unsigned short)((u + 0x7FFFu + ((u >> 16) & 1u)) >> 16);  // RNE
}

__device__ __forceinline__ bf16x8 pack8(float4 a, float4 b) {
  short8v t;
  t[0] = (short)f2bf(a.x); t[1] = (short)f2bf(a.y);
  t[2] = (short)f2bf(a.z); t[3] = (short)f2bf(a.w);
  t[4] = (short)f2bf(b.x); t[5] = (short)f2bf(b.y);
  t[6] = (short)f2bf(b.z); t[7] = (short)f2bf(b.w);
  return __builtin_bit_cast(bf16x8, t);
}

__device__ __forceinline__ float fast_sigmoid(float x) {
  float e = __builtin_amdgcn_exp2f(-1.4426950408889634f * x);   // e^-x
  return __builtin_amdgcn_rcpf(1.0f + e);
}
__device__ __forceinline__ float fast_tanh(float x) {
  float e = __builtin_amdgcn_exp2f(2.8853900817779268f * x);    // e^(2x)
  return 1.0f - 2.0f * __builtin_amdgcn_rcpf(1.0f + e);
}

// Raw barrier: waits LDS ops only; global loads (vmcnt) stay in flight.
__device__ __forceinline__ void barrier_lds() {
  asm volatile("s_waitcnt lgkmcnt(0)\n\ts_barrier" ::: "memory");
}

__global__ __launch_bounds__(256, 1)
void augru_kernel(const float* __restrict__ inputs,
                  const float* __restrict__ attn,
                  const float* __restrict__ Wz, const float* __restrict__ bz,
                  const float* __restrict__ Wr, const float* __restrict__ br,
                  const float* __restrict__ Wh, const float* __restrict__ bh,
                  float* __restrict__ out) {
  __shared__ __align__(16) short lds_a[16 * LDA_STRIDE];  // bf16 bits: [h | rh]
  __shared__ float lds_att[16 * LATT_STRIDE];             // f32 attention slice

  const int tid = threadIdx.x;
  const int w   = tid >> 6;        // wave 0..3
  const int l   = tid & 63;
  const int l15 = l & 15;
  const int lk  = l >> 4;          // k-group 0..3
  const int r0  = blockIdx.x * 16; // batch row base

  // ---- prologue: attention slice -> LDS, zero h(bf16) ----
  for (int idx = tid; idx < 16 * T_N; idx += 256) {
    int row = idx / T_N, t = idx - row * T_N;
    lds_att[row * LATT_STRIDE + t] = attn[(size_t)(r0 + row) * T_N + t];
  }
  for (int idx = tid; idx < 16 * H_DIM; idx += 256) {
    int row = idx >> 7, c = idx & 127;
    lds_a[row * LDA_STRIDE + c] = 0;
  }

  // ---- weights -> VGPR fragments ----
  // Wave w owns output cols [w*32, w*32+32) in ALL phases.
  // phase1: ct=0,1 -> z cols w*32+ct*16+l15 ; ct=2,3 -> r cols w*32+(ct-2)*16+l15
  bf16x8 w1[32];
  float  bias1[4];
  #pragma unroll
  for (int ct = 0; ct < 4; ++ct) {
    int n = w * 32 + (ct & 1) * 16 + l15;
    const float* Wp;
    float bv;
    if (ct < 2) { Wp = Wz + (size_t)n * 256; bv = bz[n]; }
    else        { Wp = Wr + (size_t)n * 256; bv = br[n]; }
    bias1[ct] = bv;
    #pragma unroll
    for (int kt = 0; kt < 8; ++kt) {
      const float* p = Wp + kt * 32 + lk * 8;
      w1[ct * 8 + kt] = pack8(*(const float4*)p, *(const float4*)(p + 4));
    }
  }
  // phase2: cols n = w*32 + ct*16 + l15 -> Wh row n
  bf16x8 w2[16];
  float  bias2[2];
  #pragma unroll
  for (int ct = 0; ct < 2; ++ct) {
    int n = w * 32 + ct * 16 + l15;
    bias2[ct] = bh[n];
    const float* Wp = Wh + (size_t)n * 256;
    #pragma unroll
    for (int kt = 0; kt < 8; ++kt) {
      const float* p = Wp + kt * 32 + lk * 8;
      w2[ct * 8 + kt] = pack8(*(const float4*)p, *(const float4*)(p + 4));
    }
  }

  // ---- per-thread f32 hidden state: h[row=lk*4+q][col=w*32+ct*16+l15] ----
  float hreg[2][4];
  #pragma unroll
  for (int ct = 0; ct < 2; ++ct)
    #pragma unroll
    for (int q = 0; q < 4; ++q) hreg[ct][q] = 0.0f;

  // ---- x fragments for t=0 (direct from global, per-wave redundant) ----
  const float* xbase = inputs + (size_t)(r0 + l15) * (T_N * I_DIM);
  bf16x8 xfrag[4];
  #pragma unroll
  for (int kt = 0; kt < 4; ++kt) {
    const float* p = xbase + kt * 32 + lk * 8;
    xfrag[kt] = pack8(*(const float4*)p, *(const float4*)(p + 4));
  }

  __syncthreads();  // prologue barrier (full sync is fine here, once)

  float4 xr0[4], xr1[4];  // raw f32 prefetch for t+1
  for (int t = 0; t < T_N; ++t) {
    // ---- (1) issue x_{t+1} prefetch; stays in flight across raw barriers ----
    if (t + 1 < T_N) {
      #pragma unroll
      for (int kt = 0; kt < 4; ++kt) {
        const float* p = xbase + (size_t)(t + 1) * I_DIM + kt * 32 + lk * 8;
        xr0[kt] = *(const float4*)p;
        xr1[kt] = *(const float4*)(p + 4);
      }
    }

    // ---- (2) issue h fragment reads + attention reads ----
    bf16x8 hfrag[4];
    #pragma unroll
    for (int kt = 0; kt < 4; ++kt)
      hfrag[kt] = *(const bf16x8*)&lds_a[l15 * LDA_STRIDE + kt * 32 + lk * 8];
    float av[4];
    #pragma unroll
    for (int q = 0; q < 4; ++q) av[q] = lds_att[(lk * 4 + q) * LATT_STRIDE + t];

    // ---- (3) phase1 x-part (no h dependency) ----
    f32x4 acc[4];
    #pragma unroll
    for (int ct = 0; ct < 4; ++ct) {
      f32x4 a; a[0] = bias1[ct]; a[1] = bias1[ct]; a[2] = bias1[ct]; a[3] = bias1[ct];
      acc[ct] = a;
    }
    #pragma unroll
    for (int kt = 0; kt < 4; ++kt)
      #pragma unroll
      for (int ct = 0; ct < 4; ++ct)
        acc[ct] = __builtin_amdgcn_mfma_f32_16x16x32_bf16(xfrag[kt], w1[ct * 8 + kt], acc[ct], 0, 0, 0);

    // ---- (4) phase2 x-part, issued early (independent of h, rh) ----
    f32x4 acc2[2];
    #pragma unroll
    for (int ct = 0; ct < 2; ++ct) {
      f32x4 a; a[0] = bias2[ct]; a[1] = bias2[ct]; a[2] = bias2[ct]; a[3] = bias2[ct];
      acc2[ct] = a;
    }
    #pragma unroll
    for (int kt = 0; kt < 4; ++kt)
      #pragma unroll
      for (int ct = 0; ct < 2; ++ct)
        acc2[ct] = __builtin_amdgcn_mfma_f32_16x16x32_bf16(xfrag[kt], w2[ct * 8 + kt], acc2[ct], 0, 0, 0);

    // ---- (5) phase1 h-part (critical chain: hfrag -> 4 MFMA) ----
    #pragma unroll
    for (int kt = 0; kt < 4; ++kt)
      #pragma unroll
      for (int ct = 0; ct < 4; ++ct)
        acc[ct] = __builtin_amdgcn_mfma_f32_16x16x32_bf16(hfrag[kt], w1[ct * 8 + 4 + kt], acc[ct], 0, 0, 0);

    // ---- (6) gates: z' to regs; rh = sigmoid(r)*h -> LDS bf16 ----
    float zp[2][4];
    #pragma unroll
    for (int ct = 0; ct < 2; ++ct) {
      int col = w * 32 + ct * 16 + l15;
      #pragma unroll
      for (int q = 0; q < 4; ++q) {
        int row = lk * 4 + q;
        zp[ct][q] = av[q] * fast_sigmoid(acc[ct][q]);          // z'
        float rr = fast_sigmoid(acc[2 + ct][q]);               // r
        lds_a[row * LDA_STRIDE + 128 + col] = (short)f2bf(rr * hreg[ct][q]);
      }
    }
    barrier_lds();  // (B1) rh visible; x prefetch still in flight

    // ---- (7) phase2 rh-part ----
    bf16x8 rfrag[4];
    #pragma unroll
    for (int kt = 0; kt < 4; ++kt)
      rfrag[kt] = *(const bf16x8*)&lds_a[l15 * LDA_STRIDE + 128 + kt * 32 + lk * 8];
    #pragma unroll
    for (int kt = 0; kt < 4; ++kt)
      #pragma unroll
      for (int ct = 0; ct < 2; ++ct)
        acc2[ct] = __builtin_amdgcn_mfma_f32_16x16x32_bf16(rfrag[kt], w2[ct * 8 + 4 + kt], acc2[ct], 0, 0, 0);

    // convert prefetched x for next step (vmcnt waits happen here, off-chain)
    if (t + 1 < T_N) {
      #pragma unroll
      for (int kt = 0; kt < 4; ++kt)
        xfrag[kt] = pack8(xr0[kt], xr1[kt]);
    }

    // ---- (8) update: h = h + z'*(tanh(pre) - h); write bf16 h for next step ----
    #pragma unroll
    for (int ct = 0; ct < 2; ++ct) {
      int col = w * 32 + ct * 16 + l15;
      #pragma unroll
      for (int q = 0; q < 4; ++q) {
        int row = lk * 4 + q;
        float ht = fast_tanh(acc2[ct][q]);
        float ho = hreg[ct][q];
        float hn = __builtin_fmaf(zp[ct][q], ht - ho, ho);
        hreg[ct][q] = hn;
        lds_a[row * LDA_STRIDE + col] = (short)f2bf(hn);
      }
    }
    barrier_lds();  // (B2) h visible for next phase1
  }

  // ---- epilogue: write final h from registers ----
  #pragma unroll
  for (int ct = 0; ct < 2; ++ct) {
    int col = w * 32 + ct * 16 + l15;
    #pragma unroll
    for (int q = 0; q < 4; ++q) {
      int row = lk * 4 + q;
      out[(size_t)(r0 + row) * H_DIM + col] = hreg[ct][q];
    }
  }
}

extern "C" void kernel_launch(void* const* d_in, const int* in_sizes, int n_in,
                              void* d_out, int out_size, void* d_ws, size_t ws_size,
                              hipStream_t stream) {
  (void)in_sizes; (void)n_in; (void)out_size; (void)d_ws; (void)ws_size;
  const float* inputs = (const float*)d_in[0];
  const float* attn   = (const float*)d_in[1];
  const float* Wz     = (const float*)d_in[2];
  const float* bz     = (const float*)d_in[3];
  const float* Wr     = (const float*)d_in[4];
  const float* br     = (const float*)d_in[5];
  const float* Wh     = (const float*)d_in[6];
  const float* bh     = (const float*)d_in[7];
  float* out = (float*)d_out;
  augru_kernel<<<64, 256, 0, stream>>>(inputs, attn, Wz, bz, Wr, br, Wh, bh, out);
}

// Round 3
// 348.908 us; speedup vs baseline: 1.1787x; 1.1759x over previous
//
#include <hip/hip_runtime.h>

// AUGRU, round 3: two-pass.
//  Pass 1 (xproj): bulk GEMM x@[Wz|Wr|Wh]_x^T + bias -> bf16 preacts in d_ws,
//                  stored in MFMA C/D fragment order for direct pass-2 loads.
//  Pass 2 (rec):   persistent recurrence, 64 blocks x 4 waves; loop holds only
//                  h-dependent MFMAs (24/step, split-k), gates, 2 raw barriers.
// Fallback: if ws_size too small, run the proven single-kernel version.

#define T_N   200
#define I_DIM 128
#define H_DIM 128
#define NBLK  64            // batch blocks (16 rows each)

typedef float  f32x4  __attribute__((ext_vector_type(4)));
typedef __bf16 bf16x4 __attribute__((ext_vector_type(4)));
typedef __bf16 bf16x8 __attribute__((ext_vector_type(8)));

#define LDA_STRIDE 264      // bf16 elems/row: [h 128 | rh 128 | pad 8]
#define LATT_STRIDE 201     // f32 attention, padded

// preact layout: [t][bblk][w][slot(6)][lane(64) x 8B]; slot = gate*2+ct,
// gate: 0=z 1=r 2=h. 8B per lane = bf16x4 (q=0..3).
#define SLOT_BYTES   512                      // 64 lanes * 8B
#define WCHUNK_BYTES (6 * SLOT_BYTES)         // 3072
#define PRE_BYTES    ((size_t)T_N * NBLK * 4 * WCHUNK_BYTES)  // 157,286,400

__device__ __forceinline__ float fast_sigmoid(float x) {
  float e = __builtin_amdgcn_exp2f(-1.4426950408889634f * x);
  return __builtin_amdgcn_rcpf(1.0f + e);
}
__device__ __forceinline__ float fast_tanh(float x) {
  float e = __builtin_amdgcn_exp2f(2.8853900817779268f * x);
  return 1.0f - 2.0f * __builtin_amdgcn_rcpf(1.0f + e);
}

// Raw barrier: waits LDS ops only; global loads (vmcnt) stay in flight.
__device__ __forceinline__ void barrier_lds() {
  asm volatile("s_waitcnt lgkmcnt(0)\n\ts_barrier" ::: "memory");
}

__device__ __forceinline__ bf16x8 pack8(float4 a, float4 b) {
  bf16x8 t;
  t[0] = (__bf16)a.x; t[1] = (__bf16)a.y; t[2] = (__bf16)a.z; t[3] = (__bf16)a.w;
  t[4] = (__bf16)b.x; t[5] = (__bf16)b.y; t[6] = (__bf16)b.z; t[7] = (__bf16)b.w;
  return t;
}

// ---------------------------------------------------------------------------
// Pass 1: x-projections. grid = 64 bblk * 25 tchunks, 256 threads.
// ---------------------------------------------------------------------------
__global__ __launch_bounds__(256, 2)
void xproj_kernel(const float* __restrict__ inputs,
                  const float* __restrict__ Wz, const float* __restrict__ bz,
                  const float* __restrict__ Wr, const float* __restrict__ br,
                  const float* __restrict__ Wh, const float* __restrict__ bh,
                  char* __restrict__ pre) {
  const int tid  = threadIdx.x;
  const int w    = tid >> 6;
  const int l    = tid & 63;
  const int l15  = l & 15;
  const int lk   = l >> 4;
  const int bblk = blockIdx.x & (NBLK - 1);
  const int t0   = (blockIdx.x >> 6) * 8;
  const int r0   = bblk * 16;

  // B-frags, x-part only (k = 0..127). slot s: gate=s>>1, ct=s&1.
  bf16x8 wb[24];
  float  bias[6];
  #pragma unroll
  for (int s = 0; s < 6; ++s) {
    int n = w * 32 + (s & 1) * 16 + l15;
    const float* Wp; float bv;
    if (s < 2)      { Wp = Wz + (size_t)n * 256; bv = bz[n]; }
    else if (s < 4) { Wp = Wr + (size_t)n * 256; bv = br[n]; }
    else            { Wp = Wh + (size_t)n * 256; bv = bh[n]; }
    bias[s] = bv;
    #pragma unroll
    for (int kt = 0; kt < 4; ++kt) {
      const float* p = Wp + kt * 32 + lk * 8;
      wb[s * 4 + kt] = pack8(*(const float4*)p, *(const float4*)(p + 4));
    }
  }

  const float* xbase = inputs + (size_t)(r0 + l15) * (T_N * I_DIM);

  #pragma unroll 2
  for (int ti = 0; ti < 8; ++ti) {
    const int t = t0 + ti;
    bf16x8 xf[4];
    #pragma unroll
    for (int kt = 0; kt < 4; ++kt) {
      const float* p = xbase + (size_t)t * I_DIM + kt * 32 + lk * 8;
      xf[kt] = pack8(*(const float4*)p, *(const float4*)(p + 4));
    }
    f32x4 acc[6];
    #pragma unroll
    for (int s = 0; s < 6; ++s) {
      f32x4 a; a[0] = bias[s]; a[1] = bias[s]; a[2] = bias[s]; a[3] = bias[s];
      acc[s] = a;
    }
    #pragma unroll
    for (int kt = 0; kt < 4; ++kt)
      #pragma unroll
      for (int s = 0; s < 6; ++s)
        acc[s] = __builtin_amdgcn_mfma_f32_16x16x32_bf16(xf[kt], wb[s * 4 + kt], acc[s], 0, 0, 0);

    char* base = pre + ((((size_t)t * NBLK + bblk) * 4 + w) * 6) * SLOT_BYTES + (size_t)l * 8;
    #pragma unroll
    for (int s = 0; s < 6; ++s) {
      bf16x4 v;
      v[0] = (__bf16)acc[s][0]; v[1] = (__bf16)acc[s][1];
      v[2] = (__bf16)acc[s][2]; v[3] = (__bf16)acc[s][3];
      *(bf16x4*)(base + s * SLOT_BYTES) = v;
    }
  }
}

// ---------------------------------------------------------------------------
// Pass 2: recurrence. grid = 64 blocks, 256 threads.
// ---------------------------------------------------------------------------
__global__ __launch_bounds__(256, 1)
void augru_rec_kernel(const char* __restrict__ pre,
                      const float* __restrict__ attn,
                      const float* __restrict__ Wz,
                      const float* __restrict__ Wr,
                      const float* __restrict__ Wh,
                      float* __restrict__ out) {
  __shared__ __align__(16) short lds_a[16 * LDA_STRIDE];  // bf16 bits: [h | rh]
  __shared__ float lds_att[16 * LATT_STRIDE];

  const int tid = threadIdx.x;
  const int w   = tid >> 6;
  const int l   = tid & 63;
  const int l15 = l & 15;
  const int lk  = l >> 4;
  const int r0  = blockIdx.x * 16;

  for (int idx = tid; idx < 16 * T_N; idx += 256) {
    int row = idx / T_N, t = idx - row * T_N;
    lds_att[row * LATT_STRIDE + t] = attn[(size_t)(r0 + row) * T_N + t];
  }
  for (int idx = tid; idx < 16 * H_DIM; idx += 256) {
    int row = idx >> 7, c = idx & 127;
    lds_a[row * LDA_STRIDE + c] = 0;
  }

  // Recurrent weights only (k = 128..255).
  // w1h[ct*4+kt]: ct 0,1 -> z cols w*32+ct*16+l15 ; ct 2,3 -> r cols w*32+(ct-2)*16+l15
  bf16x8 w1h[16];
  #pragma unroll
  for (int ct = 0; ct < 4; ++ct) {
    int n = w * 32 + (ct & 1) * 16 + l15;
    const float* Wp = (ct < 2 ? Wz : Wr) + (size_t)n * 256 + 128;
    #pragma unroll
    for (int kt = 0; kt < 4; ++kt) {
      const float* p = Wp + kt * 32 + lk * 8;
      w1h[ct * 4 + kt] = pack8(*(const float4*)p, *(const float4*)(p + 4));
    }
  }
  bf16x8 w2h[8];
  #pragma unroll
  for (int ct = 0; ct < 2; ++ct) {
    int n = w * 32 + ct * 16 + l15;
    const float* Wp = Wh + (size_t)n * 256 + 128;
    #pragma unroll
    for (int kt = 0; kt < 4; ++kt) {
      const float* p = Wp + kt * 32 + lk * 8;
      w2h[ct * 4 + kt] = pack8(*(const float4*)p, *(const float4*)(p + 4));
    }
  }

  float hreg[2][4];
  #pragma unroll
  for (int ct = 0; ct < 2; ++ct)
    #pragma unroll
    for (int q = 0; q < 4; ++q) hreg[ct][q] = 0.0f;

  // preact prefetch ring, 2 steps deep. 6 slots x 8B per step.
  const char* pbase = pre + ((size_t)blockIdx.x * 4 + w) * WCHUNK_BYTES + (size_t)l * 8;
  const size_t tstride = (size_t)NBLK * 4 * WCHUNK_BYTES;
  bf16x4 pf[2][6];
  #pragma unroll
  for (int s = 0; s < 6; ++s) {
    pf[0][s] = *(const bf16x4*)(pbase + 0 * tstride + s * SLOT_BYTES);
    pf[1][s] = *(const bf16x4*)(pbase + 1 * tstride + s * SLOT_BYTES);
  }

  __syncthreads();

  #pragma unroll 2
  for (int t = 0; t < T_N; ++t) {
    // ---- consume preact t (in regs for ~2 steps already) ----
    float pz[2][4], pr[2][4], ph[2][4];
    #pragma unroll
    for (int ct = 0; ct < 2; ++ct)
      #pragma unroll
      for (int q = 0; q < 4; ++q) {
        pz[ct][q] = (float)pf[t & 1][0 + ct][q];
        pr[ct][q] = (float)pf[t & 1][2 + ct][q];
        ph[ct][q] = (float)pf[t & 1][4 + ct][q];
      }
    // ---- issue prefetch t+2 into the slot just freed ----
    if (t + 2 < T_N) {
      #pragma unroll
      for (int s = 0; s < 6; ++s)
        pf[t & 1][s] = *(const bf16x4*)(pbase + (size_t)(t + 2) * tstride + s * SLOT_BYTES);
    }

    // ---- h fragments + attention ----
    bf16x8 hfrag[4];
    #pragma unroll
    for (int kt = 0; kt < 4; ++kt)
      hfrag[kt] = *(const bf16x8*)&lds_a[l15 * LDA_STRIDE + kt * 32 + lk * 8];
    float av[4];
    #pragma unroll
    for (int q = 0; q < 4; ++q) av[q] = lds_att[(lk * 4 + q) * LATT_STRIDE + t];

    // ---- phase 1: z,r = preact + h @ W_h^T   (split-k, chain depth 2) ----
    f32x4 accA[4], accB[4];
    #pragma unroll
    for (int ct = 0; ct < 4; ++ct) {
      float* src = (ct < 2) ? pz[ct] : pr[ct - 2];
      f32x4 a; a[0] = src[0]; a[1] = src[1]; a[2] = src[2]; a[3] = src[3];
      accA[ct] = a;
      f32x4 z4; z4[0] = 0.f; z4[1] = 0.f; z4[2] = 0.f; z4[3] = 0.f;
      accB[ct] = z4;
    }
    #pragma unroll
    for (int ct = 0; ct < 4; ++ct) {
      accA[ct] = __builtin_amdgcn_mfma_f32_16x16x32_bf16(hfrag[0], w1h[ct * 4 + 0], accA[ct], 0, 0, 0);
      accB[ct] = __builtin_amdgcn_mfma_f32_16x16x32_bf16(hfrag[2], w1h[ct * 4 + 2], accB[ct], 0, 0, 0);
    }
    #pragma unroll
    for (int ct = 0; ct < 4; ++ct) {
      accA[ct] = __builtin_amdgcn_mfma_f32_16x16x32_bf16(hfrag[1], w1h[ct * 4 + 1], accA[ct], 0, 0, 0);
      accB[ct] = __builtin_amdgcn_mfma_f32_16x16x32_bf16(hfrag[3], w1h[ct * 4 + 3], accB[ct], 0, 0, 0);
    }

    // ---- gates: z' to regs; rh -> LDS bf16 ----
    float zp[2][4];
    #pragma unroll
    for (int ct = 0; ct < 2; ++ct) {
      int col = w * 32 + ct * 16 + l15;
      #pragma unroll
      for (int q = 0; q < 4; ++q) {
        int row = lk * 4 + q;
        zp[ct][q] = av[q] * fast_sigmoid(accA[ct][q] + accB[ct][q]);
        float rr  = fast_sigmoid(accA[2 + ct][q] + accB[2 + ct][q]);
        __bf16 rhb = (__bf16)(rr * hreg[ct][q]);
        lds_a[row * LDA_STRIDE + 128 + col] = __builtin_bit_cast(short, rhb);
      }
    }
    barrier_lds();  // (B1) rh visible; global prefetch stays in flight

    // ---- phase 2: h~ = preact + rh @ Wh_h^T  (split-k) ----
    bf16x8 rfrag[4];
    #pragma unroll
    for (int kt = 0; kt < 4; ++kt)
      rfrag[kt] = *(const bf16x8*)&lds_a[l15 * LDA_STRIDE + 128 + kt * 32 + lk * 8];

    f32x4 accA2[2], accB2[2];
    #pragma unroll
    for (int ct = 0; ct < 2; ++ct) {
      f32x4 a; a[0] = ph[ct][0]; a[1] = ph[ct][1]; a[2] = ph[ct][2]; a[3] = ph[ct][3];
      accA2[ct] = a;
      f32x4 z4; z4[0] = 0.f; z4[1] = 0.f; z4[2] = 0.f; z4[3] = 0.f;
      accB2[ct] = z4;
    }
    #pragma unroll
    for (int ct = 0; ct < 2; ++ct) {
      accA2[ct] = __builtin_amdgcn_mfma_f32_16x16x32_bf16(rfrag[0], w2h[ct * 4 + 0], accA2[ct], 0, 0, 0);
      accB2[ct] = __builtin_amdgcn_mfma_f32_16x16x32_bf16(rfrag[2], w2h[ct * 4 + 2], accB2[ct], 0, 0, 0);
    }
    #pragma unroll
    for (int ct = 0; ct < 2; ++ct) {
      accA2[ct] = __builtin_amdgcn_mfma_f32_16x16x32_bf16(rfrag[1], w2h[ct * 4 + 1], accA2[ct], 0, 0, 0);
      accB2[ct] = __builtin_amdgcn_mfma_f32_16x16x32_bf16(rfrag[3], w2h[ct * 4 + 3], accB2[ct], 0, 0, 0);
    }

    // ---- update h ----
    #pragma unroll
    for (int ct = 0; ct < 2; ++ct) {
      int col = w * 32 + ct * 16 + l15;
      #pragma unroll
      for (int q = 0; q < 4; ++q) {
        int row = lk * 4 + q;
        float ht = fast_tanh(accA2[ct][q] + accB2[ct][q]);
        float ho = hreg[ct][q];
        float hn = __builtin_fmaf(zp[ct][q], ht - ho, ho);
        hreg[ct][q] = hn;
        __bf16 hb = (__bf16)hn;
        lds_a[row * LDA_STRIDE + col] = __builtin_bit_cast(short, hb);
      }
    }
    barrier_lds();  // (B2) h visible for next phase 1
  }

  #pragma unroll
  for (int ct = 0; ct < 2; ++ct) {
    int col = w * 32 + ct * 16 + l15;
    #pragma unroll
    for (int q = 0; q < 4; ++q) {
      int row = lk * 4 + q;
      out[(size_t)(r0 + row) * H_DIM + col] = hreg[ct][q];
    }
  }
}

// ---------------------------------------------------------------------------
// Fallback: proven single-kernel version (round 2, 410 us).
// ---------------------------------------------------------------------------
__global__ __launch_bounds__(256, 1)
void augru_kernel(const float* __restrict__ inputs,
                  const float* __restrict__ attn,
                  const float* __restrict__ Wz, const float* __restrict__ bz,
                  const float* __restrict__ Wr, const float* __restrict__ br,
                  const float* __restrict__ Wh, const float* __restrict__ bh,
                  float* __restrict__ out) {
  __shared__ __align__(16) short lds_a[16 * LDA_STRIDE];
  __shared__ float lds_att[16 * LATT_STRIDE];

  const int tid = threadIdx.x;
  const int w   = tid >> 6;
  const int l   = tid & 63;
  const int l15 = l & 15;
  const int lk  = l >> 4;
  const int r0  = blockIdx.x * 16;

  for (int idx = tid; idx < 16 * T_N; idx += 256) {
    int row = idx / T_N, t = idx - row * T_N;
    lds_att[row * LATT_STRIDE + t] = attn[(size_t)(r0 + row) * T_N + t];
  }
  for (int idx = tid; idx < 16 * H_DIM; idx += 256) {
    int row = idx >> 7, c = idx & 127;
    lds_a[row * LDA_STRIDE + c] = 0;
  }

  bf16x8 w1[32];
  float  bias1[4];
  #pragma unroll
  for (int ct = 0; ct < 4; ++ct) {
    int n = w * 32 + (ct & 1) * 16 + l15;
    const float* Wp; float bv;
    if (ct < 2) { Wp = Wz + (size_t)n * 256; bv = bz[n]; }
    else        { Wp = Wr + (size_t)n * 256; bv = br[n]; }
    bias1[ct] = bv;
    #pragma unroll
    for (int kt = 0; kt < 8; ++kt) {
      const float* p = Wp + kt * 32 + lk * 8;
      w1[ct * 8 + kt] = pack8(*(const float4*)p, *(const float4*)(p + 4));
    }
  }
  bf16x8 w2[16];
  float  bias2[2];
  #pragma unroll
  for (int ct = 0; ct < 2; ++ct) {
    int n = w * 32 + ct * 16 + l15;
    bias2[ct] = bh[n];
    const float* Wp = Wh + (size_t)n * 256;
    #pragma unroll
    for (int kt = 0; kt < 8; ++kt) {
      const float* p = Wp + kt * 32 + lk * 8;
      w2[ct * 8 + kt] = pack8(*(const float4*)p, *(const float4*)(p + 4));
    }
  }

  float hreg[2][4];
  #pragma unroll
  for (int ct = 0; ct < 2; ++ct)
    #pragma unroll
    for (int q = 0; q < 4; ++q) hreg[ct][q] = 0.0f;

  const float* xbase = inputs + (size_t)(r0 + l15) * (T_N * I_DIM);
  bf16x8 xfrag[4];
  #pragma unroll
  for (int kt = 0; kt < 4; ++kt) {
    const float* p = xbase + kt * 32 + lk * 8;
    xfrag[kt] = pack8(*(const float4*)p, *(const float4*)(p + 4));
  }

  __syncthreads();

  float4 xr0[4], xr1[4];
  for (int t = 0; t < T_N; ++t) {
    if (t + 1 < T_N) {
      #pragma unroll
      for (int kt = 0; kt < 4; ++kt) {
        const float* p = xbase + (size_t)(t + 1) * I_DIM + kt * 32 + lk * 8;
        xr0[kt] = *(const float4*)p;
        xr1[kt] = *(const float4*)(p + 4);
      }
    }
    bf16x8 hfrag[4];
    #pragma unroll
    for (int kt = 0; kt < 4; ++kt)
      hfrag[kt] = *(const bf16x8*)&lds_a[l15 * LDA_STRIDE + kt * 32 + lk * 8];
    float av[4];
    #pragma unroll
    for (int q = 0; q < 4; ++q) av[q] = lds_att[(lk * 4 + q) * LATT_STRIDE + t];

    f32x4 acc[4];
    #pragma unroll
    for (int ct = 0; ct < 4; ++ct) {
      f32x4 a; a[0] = bias1[ct]; a[1] = bias1[ct]; a[2] = bias1[ct]; a[3] = bias1[ct];
      acc[ct] = a;
    }
    #pragma unroll
    for (int kt = 0; kt < 4; ++kt)
      #pragma unroll
      for (int ct = 0; ct < 4; ++ct)
        acc[ct] = __builtin_amdgcn_mfma_f32_16x16x32_bf16(xfrag[kt], w1[ct * 8 + kt], acc[ct], 0, 0, 0);

    f32x4 acc2[2];
    #pragma unroll
    for (int ct = 0; ct < 2; ++ct) {
      f32x4 a; a[0] = bias2[ct]; a[1] = bias2[ct]; a[2] = bias2[ct]; a[3] = bias2[ct];
      acc2[ct] = a;
    }
    #pragma unroll
    for (int kt = 0; kt < 4; ++kt)
      #pragma unroll
      for (int ct = 0; ct < 2; ++ct)
        acc2[ct] = __builtin_amdgcn_mfma_f32_16x16x32_bf16(xfrag[kt], w2[ct * 8 + kt], acc2[ct], 0, 0, 0);

    #pragma unroll
    for (int kt = 0; kt < 4; ++kt)
      #pragma unroll
      for (int ct = 0; ct < 4; ++ct)
        acc[ct] = __builtin_amdgcn_mfma_f32_16x16x32_bf16(hfrag[kt], w1[ct * 8 + 4 + kt], acc[ct], 0, 0, 0);

    float zp[2][4];
    #pragma unroll
    for (int ct = 0; ct < 2; ++ct) {
      int col = w * 32 + ct * 16 + l15;
      #pragma unroll
      for (int q = 0; q < 4; ++q) {
        int row = lk * 4 + q;
        zp[ct][q] = av[q] * fast_sigmoid(acc[ct][q]);
        float rr = fast_sigmoid(acc[2 + ct][q]);
        __bf16 rhb = (__bf16)(rr * hreg[ct][q]);
        lds_a[row * LDA_STRIDE + 128 + col] = __builtin_bit_cast(short, rhb);
      }
    }
    barrier_lds();

    bf16x8 rfrag[4];
    #pragma unroll
    for (int kt = 0; kt < 4; ++kt)
      rfrag[kt] = *(const bf16x8*)&lds_a[l15 * LDA_STRIDE + 128 + kt * 32 + lk * 8];
    #pragma unroll
    for (int kt = 0; kt < 4; ++kt)
      #pragma unroll
      for (int ct = 0; ct < 2; ++ct)
        acc2[ct] = __builtin_amdgcn_mfma_f32_16x16x32_bf16(rfrag[kt], w2[ct * 8 + 4 + kt], acc2[ct], 0, 0, 0);

    if (t + 1 < T_N) {
      #pragma unroll
      for (int kt = 0; kt < 4; ++kt)
        xfrag[kt] = pack8(xr0[kt], xr1[kt]);
    }

    #pragma unroll
    for (int ct = 0; ct < 2; ++ct) {
      int col = w * 32 + ct * 16 + l15;
      #pragma unroll
      for (int q = 0; q < 4; ++q) {
        int row = lk * 4 + q;
        float ht = fast_tanh(acc2[ct][q]);
        float ho = hreg[ct][q];
        float hn = __builtin_fmaf(zp[ct][q], ht - ho, ho);
        hreg[ct][q] = hn;
        __bf16 hb = (__bf16)hn;
        lds_a[row * LDA_STRIDE + col] = __builtin_bit_cast(short, hb);
      }
    }
    barrier_lds();
  }

  #pragma unroll
  for (int ct = 0; ct < 2; ++ct) {
    int col = w * 32 + ct * 16 + l15;
    #pragma unroll
    for (int q = 0; q < 4; ++q) {
      int row = lk * 4 + q;
      out[(size_t)(r0 + row) * H_DIM + col] = hreg[ct][q];
    }
  }
}

extern "C" void kernel_launch(void* const* d_in, const int* in_sizes, int n_in,
                              void* d_out, int out_size, void* d_ws, size_t ws_size,
                              hipStream_t stream) {
  (void)in_sizes; (void)n_in; (void)out_size;
  const float* inputs = (const float*)d_in[0];
  const float* attn   = (const float*)d_in[1];
  const float* Wz     = (const float*)d_in[2];
  const float* bz     = (const float*)d_in[3];
  const float* Wr     = (const float*)d_in[4];
  const float* br     = (const float*)d_in[5];
  const float* Wh     = (const float*)d_in[6];
  const float* bh     = (const float*)d_in[7];
  float* out = (float*)d_out;

  if (ws_size >= PRE_BYTES) {
    char* pre = (char*)d_ws;
    xproj_kernel<<<NBLK * (T_N / 8), 256, 0, stream>>>(inputs, Wz, bz, Wr, br, Wh, bh, pre);
    augru_rec_kernel<<<NBLK, 256, 0, stream>>>(pre, attn, Wz, Wr, Wh, out);
  } else {
    augru_kernel<<<NBLK, 256, 0, stream>>>(inputs, attn, Wz, bz, Wr, br, Wh, bh, out);
  }
}

// Round 4
// 286.070 us; speedup vs baseline: 1.4376x; 1.2197x over previous
//
#include <hip/hip_runtime.h>

// AUGRU, round 4: two-pass, 8-wave recurrence.
//  Pass 1 (xproj): bulk GEMM x@[Wz|Wr|Wh]_x^T + bias -> bf16 preacts in d_ws,
//                  layout [t][bblk][gate(3)][col(128)][row4(4x bf16)].
//  Pass 2 (rec):   persistent recurrence, 64 blocks x 8 waves (512 thr):
//                  waves 0-3 own z cols, 4-7 own r cols in phase1 (8 MFMA each);
//                  every wave owns 16 cols in phase2 (4 MFMA each).
//                  2 waves/SIMD -> MFMA/VALU/trans pipes overlap.
// Fallback: proven single-kernel (R2) if ws too small.

#define T_N   200
#define I_DIM 128
#define H_DIM 128
#define NBLK  64

typedef float  f32x4  __attribute__((ext_vector_type(4)));
typedef __bf16 bf16x4 __attribute__((ext_vector_type(4)));
typedef __bf16 bf16x8 __attribute__((ext_vector_type(8)));

#define LDA_STRIDE 264      // bf16: [h 128 | rh 128 | pad 8]
#define LDF_STRIDE 132      // f32 h / z' mirrors
#define LATT_STRIDE 201

// preact: per (t,bblk): 3 gates * 128 cols * 16 rows * 2B = 12288 B
#define GATE_BYTES 4096
#define PB_BYTES   (3 * GATE_BYTES)
#define PRE_BYTES  ((size_t)T_N * NBLK * PB_BYTES)   // 157,286,400

__device__ __forceinline__ float fast_sigmoid(float x) {
  float e = __builtin_amdgcn_exp2f(-1.4426950408889634f * x);
  return __builtin_amdgcn_rcpf(1.0f + e);
}
__device__ __forceinline__ float fast_tanh(float x) {
  float e = __builtin_amdgcn_exp2f(2.8853900817779268f * x);
  return 1.0f - 2.0f * __builtin_amdgcn_rcpf(1.0f + e);
}
__device__ __forceinline__ void barrier_lds() {
  asm volatile("s_waitcnt lgkmcnt(0)\n\ts_barrier" ::: "memory");
}
__device__ __forceinline__ bf16x8 pack8(float4 a, float4 b) {
  bf16x8 t;
  t[0] = (__bf16)a.x; t[1] = (__bf16)a.y; t[2] = (__bf16)a.z; t[3] = (__bf16)a.w;
  t[4] = (__bf16)b.x; t[5] = (__bf16)b.y; t[6] = (__bf16)b.z; t[7] = (__bf16)b.w;
  return t;
}

// ---------------------------------------------------------------------------
// Pass 1: x-projections. grid = 64 bblk * 8 tchunks (25 t each), 256 threads.
// ---------------------------------------------------------------------------
#define TCHUNK 25
__global__ __launch_bounds__(256, 2)
void xproj_kernel(const float* __restrict__ inputs,
                  const float* __restrict__ Wz, const float* __restrict__ bz,
                  const float* __restrict__ Wr, const float* __restrict__ br,
                  const float* __restrict__ Wh, const float* __restrict__ bh,
                  char* __restrict__ pre) {
  const int tid  = threadIdx.x;
  const int w    = tid >> 6;
  const int l    = tid & 63;
  const int l15  = l & 15;
  const int lk   = l >> 4;
  const int bblk = blockIdx.x & (NBLK - 1);
  const int t0   = (blockIdx.x >> 6) * TCHUNK;
  const int r0   = bblk * 16;

  // B-frags, x-part (k=0..127). slot s: gate=s>>1, ct=s&1.
  bf16x8 wb[24];
  float  bias[6];
  #pragma unroll
  for (int s = 0; s < 6; ++s) {
    int n = w * 32 + (s & 1) * 16 + l15;
    const float* Wp; float bv;
    if (s < 2)      { Wp = Wz + (size_t)n * 256; bv = bz[n]; }
    else if (s < 4) { Wp = Wr + (size_t)n * 256; bv = br[n]; }
    else            { Wp = Wh + (size_t)n * 256; bv = bh[n]; }
    bias[s] = bv;
    #pragma unroll
    for (int kt = 0; kt < 4; ++kt) {
      const float* p = Wp + kt * 32 + lk * 8;
      wb[s * 4 + kt] = pack8(*(const float4*)p, *(const float4*)(p + 4));
    }
  }

  const float* xbase = inputs + (size_t)(r0 + l15) * (T_N * I_DIM);

  #pragma unroll 2
  for (int ti = 0; ti < TCHUNK; ++ti) {
    const int t = t0 + ti;
    bf16x8 xf[4];
    #pragma unroll
    for (int kt = 0; kt < 4; ++kt) {
      const float* p = xbase + (size_t)t * I_DIM + kt * 32 + lk * 8;
      xf[kt] = pack8(*(const float4*)p, *(const float4*)(p + 4));
    }
    f32x4 acc[6];
    #pragma unroll
    for (int s = 0; s < 6; ++s) {
      f32x4 a; a[0] = bias[s]; a[1] = bias[s]; a[2] = bias[s]; a[3] = bias[s];
      acc[s] = a;
    }
    #pragma unroll
    for (int kt = 0; kt < 4; ++kt)
      #pragma unroll
      for (int s = 0; s < 6; ++s)
        acc[s] = __builtin_amdgcn_mfma_f32_16x16x32_bf16(xf[kt], wb[s * 4 + kt], acc[s], 0, 0, 0);

    // store: [t][bblk][gate][col][row4] ; col = w*32+(s&1)*16+l15, rows lk*4..+3
    char* base = pre + ((size_t)t * NBLK + bblk) * PB_BYTES;
    #pragma unroll
    for (int s = 0; s < 6; ++s) {
      int g   = s >> 1;
      int col = w * 32 + (s & 1) * 16 + l15;
      bf16x4 v;
      v[0] = (__bf16)acc[s][0]; v[1] = (__bf16)acc[s][1];
      v[2] = (__bf16)acc[s][2]; v[3] = (__bf16)acc[s][3];
      *(bf16x4*)(base + g * GATE_BYTES + col * 32 + lk * 8) = v;
    }
  }
}

// ---------------------------------------------------------------------------
// Pass 2: recurrence. grid = 64 blocks, 512 threads (8 waves).
// ---------------------------------------------------------------------------
__global__ __launch_bounds__(512, 2)
void augru_rec_kernel(const char* __restrict__ pre,
                      const float* __restrict__ attn,
                      const float* __restrict__ Wz,
                      const float* __restrict__ Wr,
                      const float* __restrict__ Wh,
                      float* __restrict__ out) {
  __shared__ __align__(16) short lds_a[16 * LDA_STRIDE];  // bf16 bits: [h | rh]
  __shared__ float lds_hf[16 * LDF_STRIDE];               // f32 h mirror
  __shared__ float lds_z[16 * LDF_STRIDE];                // f32 z' = a*sigmoid(z)
  __shared__ float lds_att[16 * LATT_STRIDE];

  const int tid  = threadIdx.x;
  const int w    = tid >> 6;          // 0..7
  const int l    = tid & 63;
  const int l15  = l & 15;
  const int lk   = l >> 4;
  const int r0   = blockIdx.x * 16;
  const bool isz = (w < 4);
  const int cb1  = (w & 3) * 32;      // phase1 col base (32 cols per wave)
  const int col2 = w * 16 + l15;      // phase2 / update col

  // ---- prologue ----
  for (int idx = tid; idx < 16 * T_N; idx += 512) {
    int row = idx / T_N, t = idx - row * T_N;
    lds_att[row * LATT_STRIDE + t] = attn[(size_t)(r0 + row) * T_N + t];
  }
  for (int idx = tid; idx < 16 * H_DIM; idx += 512) {
    int row = idx >> 7, c = idx & 127;
    lds_a[row * LDA_STRIDE + c] = 0;
    lds_hf[row * LDF_STRIDE + c] = 0.0f;
  }

  // ---- recurrent weight fragments (k = 128..255) ----
  // phase1: wave gate = z (w<4) or r; cols cb1 + ct*16 + l15, ct = 0,1
  const float* W1 = isz ? Wz : Wr;
  bf16x8 w1h[8];
  #pragma unroll
  for (int ct = 0; ct < 2; ++ct) {
    int n = cb1 + ct * 16 + l15;
    const float* Wp = W1 + (size_t)n * 256 + 128;
    #pragma unroll
    for (int kt = 0; kt < 4; ++kt) {
      const float* p = Wp + kt * 32 + lk * 8;
      w1h[ct * 4 + kt] = pack8(*(const float4*)p, *(const float4*)(p + 4));
    }
  }
  // phase2: col2 of Wh
  bf16x8 w2h[4];
  {
    const float* Wp = Wh + (size_t)col2 * 256 + 128;
    #pragma unroll
    for (int kt = 0; kt < 4; ++kt) {
      const float* p = Wp + kt * 32 + lk * 8;
      w2h[kt] = pack8(*(const float4*)p, *(const float4*)(p + 4));
    }
  }

  float hreg[4];
  #pragma unroll
  for (int q = 0; q < 4; ++q) hreg[q] = 0.0f;

  // ---- preact pointers + 2-deep ring ----
  const size_t tstride = (size_t)NBLK * PB_BYTES;
  const char* pg = pre + (size_t)blockIdx.x * PB_BYTES + (isz ? 0 : GATE_BYTES)
                 + (size_t)(cb1 + l15) * 32 + lk * 8;          // ct stride = 512B
  const char* ph = pre + (size_t)blockIdx.x * PB_BYTES + 2 * GATE_BYTES
                 + (size_t)col2 * 32 + lk * 8;
  bf16x4 pf[2][3];
  #pragma unroll
  for (int d = 0; d < 2; ++d) {
    pf[d][0] = *(const bf16x4*)(pg + d * tstride);
    pf[d][1] = *(const bf16x4*)(pg + d * tstride + 512);
    pf[d][2] = *(const bf16x4*)(ph + d * tstride);
  }

  __syncthreads();

  #pragma unroll 2
  for (int t = 0; t < T_N; ++t) {
    // consume preact t
    float p1[2][4], phv[4];
    #pragma unroll
    for (int ct = 0; ct < 2; ++ct)
      #pragma unroll
      for (int q = 0; q < 4; ++q) p1[ct][q] = (float)pf[t & 1][ct][q];
    #pragma unroll
    for (int q = 0; q < 4; ++q) phv[q] = (float)pf[t & 1][2][q];
    // prefetch t+2
    if (t + 2 < T_N) {
      const char* b = pg + (size_t)(t + 2) * tstride;
      pf[t & 1][0] = *(const bf16x4*)b;
      pf[t & 1][1] = *(const bf16x4*)(b + 512);
      pf[t & 1][2] = *(const bf16x4*)(ph + (size_t)(t + 2) * tstride);
    }

    // h fragments (A-operand) + per-role LDS reads
    bf16x8 hfrag[4];
    #pragma unroll
    for (int kt = 0; kt < 4; ++kt)
      hfrag[kt] = *(const bf16x8*)&lds_a[l15 * LDA_STRIDE + kt * 32 + lk * 8];
    float av[4], hpre[2][4];
    if (isz) {
      #pragma unroll
      for (int q = 0; q < 4; ++q) av[q] = lds_att[(lk * 4 + q) * LATT_STRIDE + t];
    } else {
      #pragma unroll
      for (int ct = 0; ct < 2; ++ct)
        #pragma unroll
        for (int q = 0; q < 4; ++q)
          hpre[ct][q] = lds_hf[(lk * 4 + q) * LDF_STRIDE + cb1 + ct * 16 + l15];
    }

    // phase 1: gate preacts + h @ W_h^T (split-k, depth 2)
    f32x4 accA[2], accB[2];
    #pragma unroll
    for (int ct = 0; ct < 2; ++ct) {
      f32x4 a; a[0] = p1[ct][0]; a[1] = p1[ct][1]; a[2] = p1[ct][2]; a[3] = p1[ct][3];
      accA[ct] = a;
      f32x4 z4; z4[0] = 0.f; z4[1] = 0.f; z4[2] = 0.f; z4[3] = 0.f;
      accB[ct] = z4;
    }
    #pragma unroll
    for (int ct = 0; ct < 2; ++ct) {
      accA[ct] = __builtin_amdgcn_mfma_f32_16x16x32_bf16(hfrag[0], w1h[ct * 4 + 0], accA[ct], 0, 0, 0);
      accB[ct] = __builtin_amdgcn_mfma_f32_16x16x32_bf16(hfrag[2], w1h[ct * 4 + 2], accB[ct], 0, 0, 0);
    }
    #pragma unroll
    for (int ct = 0; ct < 2; ++ct) {
      accA[ct] = __builtin_amdgcn_mfma_f32_16x16x32_bf16(hfrag[1], w1h[ct * 4 + 1], accA[ct], 0, 0, 0);
      accB[ct] = __builtin_amdgcn_mfma_f32_16x16x32_bf16(hfrag[3], w1h[ct * 4 + 3], accB[ct], 0, 0, 0);
    }

    // gates
    if (isz) {
      #pragma unroll
      for (int ct = 0; ct < 2; ++ct)
        #pragma unroll
        for (int q = 0; q < 4; ++q)
          lds_z[(lk * 4 + q) * LDF_STRIDE + cb1 + ct * 16 + l15] =
              av[q] * fast_sigmoid(accA[ct][q] + accB[ct][q]);
    } else {
      #pragma unroll
      for (int ct = 0; ct < 2; ++ct)
        #pragma unroll
        for (int q = 0; q < 4; ++q) {
          float rr = fast_sigmoid(accA[ct][q] + accB[ct][q]);
          __bf16 rhb = (__bf16)(rr * hpre[ct][q]);
          lds_a[(lk * 4 + q) * LDA_STRIDE + 128 + cb1 + ct * 16 + l15] =
              __builtin_bit_cast(short, rhb);
        }
    }
    barrier_lds();  // B1: rh + z' visible; global prefetch in flight

    // phase 2: h~ = preact + rh @ Wh_h^T (split-k, depth 2)
    bf16x8 rfrag[4];
    #pragma unroll
    for (int kt = 0; kt < 4; ++kt)
      rfrag[kt] = *(const bf16x8*)&lds_a[l15 * LDA_STRIDE + 128 + kt * 32 + lk * 8];
    float zpv[4];
    #pragma unroll
    for (int q = 0; q < 4; ++q) zpv[q] = lds_z[(lk * 4 + q) * LDF_STRIDE + col2];

    f32x4 aA, aB;
    { f32x4 a; a[0] = phv[0]; a[1] = phv[1]; a[2] = phv[2]; a[3] = phv[3]; aA = a; }
    { f32x4 z4; z4[0] = 0.f; z4[1] = 0.f; z4[2] = 0.f; z4[3] = 0.f; aB = z4; }
    aA = __builtin_amdgcn_mfma_f32_16x16x32_bf16(rfrag[0], w2h[0], aA, 0, 0, 0);
    aB = __builtin_amdgcn_mfma_f32_16x16x32_bf16(rfrag[2], w2h[2], aB, 0, 0, 0);
    aA = __builtin_amdgcn_mfma_f32_16x16x32_bf16(rfrag[1], w2h[1], aA, 0, 0, 0);
    aB = __builtin_amdgcn_mfma_f32_16x16x32_bf16(rfrag[3], w2h[3], aB, 0, 0, 0);

    // update h
    #pragma unroll
    for (int q = 0; q < 4; ++q) {
      int row = lk * 4 + q;
      float ht = fast_tanh(aA[q] + aB[q]);
      float ho = hreg[q];
      float hn = __builtin_fmaf(zpv[q], ht - ho, ho);
      hreg[q] = hn;
      lds_hf[row * LDF_STRIDE + col2] = hn;
      __bf16 hb = (__bf16)hn;
      lds_a[row * LDA_STRIDE + col2] = __builtin_bit_cast(short, hb);
    }
    barrier_lds();  // B2: h visible for next phase1
  }

  #pragma unroll
  for (int q = 0; q < 4; ++q)
    out[(size_t)(r0 + lk * 4 + q) * H_DIM + col2] = hreg[q];
}

// ---------------------------------------------------------------------------
// Fallback: proven single-kernel version (round 2).
// ---------------------------------------------------------------------------
__global__ __launch_bounds__(256, 1)
void augru_kernel(const float* __restrict__ inputs,
                  const float* __restrict__ attn,
                  const float* __restrict__ Wz, const float* __restrict__ bz,
                  const float* __restrict__ Wr, const float* __restrict__ br,
                  const float* __restrict__ Wh, const float* __restrict__ bh,
                  float* __restrict__ out) {
  __shared__ __align__(16) short lds_a[16 * LDA_STRIDE];
  __shared__ float lds_att[16 * LATT_STRIDE];

  const int tid = threadIdx.x;
  const int w   = tid >> 6;
  const int l   = tid & 63;
  const int l15 = l & 15;
  const int lk  = l >> 4;
  const int r0  = blockIdx.x * 16;

  for (int idx = tid; idx < 16 * T_N; idx += 256) {
    int row = idx / T_N, t = idx - row * T_N;
    lds_att[row * LATT_STRIDE + t] = attn[(size_t)(r0 + row) * T_N + t];
  }
  for (int idx = tid; idx < 16 * H_DIM; idx += 256) {
    int row = idx >> 7, c = idx & 127;
    lds_a[row * LDA_STRIDE + c] = 0;
  }

  bf16x8 w1[32];
  float  bias1[4];
  #pragma unroll
  for (int ct = 0; ct < 4; ++ct) {
    int n = w * 32 + (ct & 1) * 16 + l15;
    const float* Wp; float bv;
    if (ct < 2) { Wp = Wz + (size_t)n * 256; bv = bz[n]; }
    else        { Wp = Wr + (size_t)n * 256; bv = br[n]; }
    bias1[ct] = bv;
    #pragma unroll
    for (int kt = 0; kt < 8; ++kt) {
      const float* p = Wp + kt * 32 + lk * 8;
      w1[ct * 8 + kt] = pack8(*(const float4*)p, *(const float4*)(p + 4));
    }
  }
  bf16x8 w2[16];
  float  bias2[2];
  #pragma unroll
  for (int ct = 0; ct < 2; ++ct) {
    int n = w * 32 + ct * 16 + l15;
    bias2[ct] = bh[n];
    const float* Wp = Wh + (size_t)n * 256;
    #pragma unroll
    for (int kt = 0; kt < 8; ++kt) {
      const float* p = Wp + kt * 32 + lk * 8;
      w2[ct * 8 + kt] = pack8(*(const float4*)p, *(const float4*)(p + 4));
    }
  }

  float hreg[2][4];
  #pragma unroll
  for (int ct = 0; ct < 2; ++ct)
    #pragma unroll
    for (int q = 0; q < 4; ++q) hreg[ct][q] = 0.0f;

  const float* xbase = inputs + (size_t)(r0 + l15) * (T_N * I_DIM);
  bf16x8 xfrag[4];
  #pragma unroll
  for (int kt = 0; kt < 4; ++kt) {
    const float* p = xbase + kt * 32 + lk * 8;
    xfrag[kt] = pack8(*(const float4*)p, *(const float4*)(p + 4));
  }

  __syncthreads();

  float4 xr0[4], xr1[4];
  for (int t = 0; t < T_N; ++t) {
    if (t + 1 < T_N) {
      #pragma unroll
      for (int kt = 0; kt < 4; ++kt) {
        const float* p = xbase + (size_t)(t + 1) * I_DIM + kt * 32 + lk * 8;
        xr0[kt] = *(const float4*)p;
        xr1[kt] = *(const float4*)(p + 4);
      }
    }
    bf16x8 hfrag[4];
    #pragma unroll
    for (int kt = 0; kt < 4; ++kt)
      hfrag[kt] = *(const bf16x8*)&lds_a[l15 * LDA_STRIDE + kt * 32 + lk * 8];
    float av[4];
    #pragma unroll
    for (int q = 0; q < 4; ++q) av[q] = lds_att[(lk * 4 + q) * LATT_STRIDE + t];

    f32x4 acc[4];
    #pragma unroll
    for (int ct = 0; ct < 4; ++ct) {
      f32x4 a; a[0] = bias1[ct]; a[1] = bias1[ct]; a[2] = bias1[ct]; a[3] = bias1[ct];
      acc[ct] = a;
    }
    #pragma unroll
    for (int kt = 0; kt < 4; ++kt)
      #pragma unroll
      for (int ct = 0; ct < 4; ++ct)
        acc[ct] = __builtin_amdgcn_mfma_f32_16x16x32_bf16(xfrag[kt], w1[ct * 8 + kt], acc[ct], 0, 0, 0);

    f32x4 acc2[2];
    #pragma unroll
    for (int ct = 0; ct < 2; ++ct) {
      f32x4 a; a[0] = bias2[ct]; a[1] = bias2[ct]; a[2] = bias2[ct]; a[3] = bias2[ct];
      acc2[ct] = a;
    }
    #pragma unroll
    for (int kt = 0; kt < 4; ++kt)
      #pragma unroll
      for (int ct = 0; ct < 2; ++ct)
        acc2[ct] = __builtin_amdgcn_mfma_f32_16x16x32_bf16(xfrag[kt], w2[ct * 8 + kt], acc2[ct], 0, 0, 0);

    #pragma unroll
    for (int kt = 0; kt < 4; ++kt)
      #pragma unroll
      for (int ct = 0; ct < 4; ++ct)
        acc[ct] = __builtin_amdgcn_mfma_f32_16x16x32_bf16(hfrag[kt], w1[ct * 8 + 4 + kt], acc[ct], 0, 0, 0);

    float zp[2][4];
    #pragma unroll
    for (int ct = 0; ct < 2; ++ct) {
      int col = w * 32 + ct * 16 + l15;
      #pragma unroll
      for (int q = 0; q < 4; ++q) {
        int row = lk * 4 + q;
        zp[ct][q] = av[q] * fast_sigmoid(acc[ct][q]);
        float rr = fast_sigmoid(acc[2 + ct][q]);
        __bf16 rhb = (__bf16)(rr * hreg[ct][q]);
        lds_a[row * LDA_STRIDE + 128 + col] = __builtin_bit_cast(short, rhb);
      }
    }
    barrier_lds();

    bf16x8 rfrag[4];
    #pragma unroll
    for (int kt = 0; kt < 4; ++kt)
      rfrag[kt] = *(const bf16x8*)&lds_a[l15 * LDA_STRIDE + 128 + kt * 32 + lk * 8];
    #pragma unroll
    for (int kt = 0; kt < 4; ++kt)
      #pragma unroll
      for (int ct = 0; ct < 2; ++ct)
        acc2[ct] = __builtin_amdgcn_mfma_f32_16x16x32_bf16(rfrag[kt], w2[ct * 8 + 4 + kt], acc2[ct], 0, 0, 0);

    if (t + 1 < T_N) {
      #pragma unroll
      for (int kt = 0; kt < 4; ++kt)
        xfrag[kt] = pack8(xr0[kt], xr1[kt]);
    }

    #pragma unroll
    for (int ct = 0; ct < 2; ++ct) {
      int col = w * 32 + ct * 16 + l15;
      #pragma unroll
      for (int q = 0; q < 4; ++q) {
        int row = lk * 4 + q;
        float ht = fast_tanh(acc2[ct][q]);
        float ho = hreg[ct][q];
        float hn = __builtin_fmaf(zp[ct][q], ht - ho, ho);
        hreg[ct][q] = hn;
        __bf16 hb = (__bf16)hn;
        lds_a[row * LDA_STRIDE + col] = __builtin_bit_cast(short, hb);
      }
    }
    barrier_lds();
  }

  #pragma unroll
  for (int ct = 0; ct < 2; ++ct) {
    int col = w * 32 + ct * 16 + l15;
    #pragma unroll
    for (int q = 0; q < 4; ++q) {
      int row = lk * 4 + q;
      out[(size_t)(r0 + row) * H_DIM + col] = hreg[ct][q];
    }
  }
}

extern "C" void kernel_launch(void* const* d_in, const int* in_sizes, int n_in,
                              void* d_out, int out_size, void* d_ws, size_t ws_size,
                              hipStream_t stream) {
  (void)in_sizes; (void)n_in; (void)out_size;
  const float* inputs = (const float*)d_in[0];
  const float* attn   = (const float*)d_in[1];
  const float* Wz     = (const float*)d_in[2];
  const float* bz     = (const float*)d_in[3];
  const float* Wr     = (const float*)d_in[4];
  const float* br     = (const float*)d_in[5];
  const float* Wh     = (const float*)d_in[6];
  const float* bh     = (const float*)d_in[7];
  float* out = (float*)d_out;

  if (ws_size >= PRE_BYTES) {
    char* pre = (char*)d_ws;
    xproj_kernel<<<NBLK * (T_N / TCHUNK), 256, 0, stream>>>(inputs, Wz, bz, Wr, br, Wh, bh, pre);
    augru_rec_kernel<<<NBLK, 512, 0, stream>>>(pre, attn, Wz, Wr, Wh, out);
  } else {
    augru_kernel<<<NBLK, 256, 0, stream>>>(inputs, attn, Wz, bz, Wr, br, Wh, bh, out);
  }
}